// Round 8
// baseline (558.848 us; speedup 1.0000x reference)
//
#include <hip/hip_runtime.h>

// SpikingConv2D: tj [16,258,258] f32, kernel [128,1,3,3] f32 (flat 9x128 view),
// D_i [9,128] f32 (row 0 only). out[n*128+f], n=(i*256+j)*16+b, Hv=256.
// ti = min(sum_t x[t]*W[t][f] + (1 - D_i[0][f]), 1.0).
//
// R10: R3 (530us, conv ~104us vs ~85us write floor) + 1024B wave-stores.
// One WAVE = one task (batch-PAIR bp -> b=2bp,2bp+1; pixel strip j0..j0+3;
// all 128 filters). Lanes 0-31 compute batch 2bp, lanes 32-63 batch 2bp+1,
// 4 filters/lane (float4). Store: 64 lanes x 16B = 1024B = rows n0,n0+1
// contiguous (addr = out4 + n0*32 + lane) -> store insts per byte halved vs
// R3, loop iters halved. Patches for BOTH batches are wave-uniform scalar
// loads (36 SGPR floats/buffer, double-buffered prefetch as in R3); the
// half-wave select is 9 cndmasks/pixel (VALU has ~4x slack). Tap order per
// filter unchanged -> bitwise-identical output.

#define B_N   16
#define S_N   258
#define HV_N  256
#define F_N   128

#define GRID      8192
#define WPB       4                                 // waves per block
#define NSTREAM   (GRID * WPB)                      // 32768 waves in flight
#define NTASK     ((HV_N * (HV_N / 4)) * (B_N / 2)) // 131072 wave-tasks

typedef float v4f __attribute__((ext_vector_type(4)));

__global__ __launch_bounds__(256, 6) void spiking_conv2d_kernel(
    const float* __restrict__ tj, const float* __restrict__ kern,
    const float* __restrict__ Di, float* __restrict__ out) {
  const int lane = threadIdx.x & 63;
  const int q    = lane & 31;        // filter quad: f = 4q..4q+3
  const bool hi  = lane >= 32;       // batch-half select
  const int wid  = __builtin_amdgcn_readfirstlane(threadIdx.x >> 6);

  // W[t][f] for f=4q..4q+3; registers, loaded once.
  float4 w[9];
#pragma unroll
  for (int t = 0; t < 9; ++t)
    w[t] = reinterpret_cast<const float4*>(kern)[t * (F_N / 4) + q];
  const float4 d = reinterpret_cast<const float4*>(Di)[q];
  const float4 thr = make_float4(1.0f - d.x, 1.0f - d.y, 1.0f - d.z, 1.0f - d.w);

  // task t: bp = t&7 (batch pair), pblk = t>>3, j0 = (pblk&63)*4, i = pblk>>6
  auto load_task = [&](int t, float (&x)[36]) {
    const int bp   = t & 7;
    const int pblk = t >> 3;
    const int j0   = (pblk & 63) << 2;
    const int i    = pblk >> 6;
#pragma unroll
    for (int h = 0; h < 2; ++h) {
      const float* s = tj + ((2 * bp + h) * S_N + i) * S_N + j0;  // wave-uniform
#pragma unroll
      for (int r = 0; r < 3; ++r)
#pragma unroll
        for (int c = 0; c < 6; ++c)
          x[h * 18 + r * 6 + c] = s[r * S_N + c];
    }
  };

  auto compute_store = [&](int t, const float (&x)[36]) {
    const int bp   = t & 7;
    const int pblk = t >> 3;
    const int j0   = (pblk & 63) << 2;
    const int i    = pblk >> 6;
    const int n0   = ((i * HV_N + j0) << 4) + 2 * bp;  // row of (pix0, b=2bp)
    // lanes 0-31 -> row n0 (float4 idx n0*32+q); lanes 32-63 -> row n0+1
    // (idx n0*32+32+q). Combined offset = n0*32 + lane: 1024B contiguous.
    v4f* o = reinterpret_cast<v4f*>(out) + (long)n0 * (F_N / 4) + lane;
#pragma unroll
    for (int p = 0; p < 4; ++p) {
      float xv[9];
#pragma unroll
      for (int r = 0; r < 3; ++r)
#pragma unroll
        for (int c = 0; c < 3; ++c)  // half-wave patch select (cndmask)
          xv[r * 3 + c] = hi ? x[18 + r * 6 + p + c] : x[r * 6 + p + c];
      float ax = thr.x, ay = thr.y, az = thr.z, aw = thr.w;
#pragma unroll
      for (int k = 0; k < 9; ++k) {  // tap order == R2/R3: bitwise-identical
        ax = fmaf(xv[k], w[k].x, ax);
        ay = fmaf(xv[k], w[k].y, ay);
        az = fmaf(xv[k], w[k].z, az);
        aw = fmaf(xv[k], w[k].w, aw);
      }
      v4f v = {fminf(ax, 1.0f), fminf(ay, 1.0f), fminf(az, 1.0f), fminf(aw, 1.0f)};
      // pixel p -> rows n0+16p, n0+16p+1 -> +p*512 float4
      __builtin_nontemporal_store(v, o + p * (16 * (F_N / 4)));
    }
  };

  float xa[36], xb[36];
  int t = blockIdx.x * WPB + wid;
  if (t >= NTASK) return;  // defensive; exact with GRID=8192
  load_task(t, xa);
#pragma unroll 1
  for (; t + NSTREAM < NTASK; ) {
    load_task(t + NSTREAM, xb);     // prefetch next while computing current
    compute_store(t, xa);
    t += NSTREAM;
    if (t + NSTREAM < NTASK) {
      load_task(t + NSTREAM, xa);   // prefetch next-next
      compute_store(t, xb);
      t += NSTREAM;
    } else {
      compute_store(t, xb);
      t += NSTREAM;  // terminates loop
    }
  }
  if (t < NTASK) compute_store(t, xa);  // tail (not hit with exact config)
}

extern "C" void kernel_launch(void* const* d_in, const int* in_sizes, int n_in,
                              void* d_out, int out_size, void* d_ws, size_t ws_size,
                              hipStream_t stream) {
  const float* tj   = (const float*)d_in[0];
  const float* kern = (const float*)d_in[1];
  const float* Di   = (const float*)d_in[2];
  float* out = (float*)d_out;
  spiking_conv2d_kernel<<<GRID, 256, 0, stream>>>(tj, kern, Di, out);
}

// Round 9
// 530.160 us; speedup vs baseline: 1.0541x; 1.0541x over previous
//
#include <hip/hip_runtime.h>

// SpikingConv2D: tj [16,258,258] f32, kernel [128,1,3,3] f32 (flat 9x128 view),
// D_i [9,128] f32 (row 0 only). out[n*128+f], n=(i*256+j)*16+b, Hv=256.
// ti = min(sum_t x[t]*W[t][f] + (1 - D_i[0][f]), 1.0).
//
// R11 = R3 (530us best: wave-per-task, scalar-path patch loads, dbuf
// prefetch) with ONE change: plain stores instead of nontemporal.
// Theory: NT bypasses L2 -> 512B wave-granules hit HBM fragmented
// (conv writes at 4.9 TB/s vs the rocclr fill's 6.2 TB/s on the same
// class of pattern); plain stores let L2 aggregate full lines.
// R10 post-mortem: batch-pair 1024B stores regressed 530->559 (72-float
// uniform state blew the SGPR budget + 36 cndmask/task); reverted.

#define B_N   16
#define S_N   258
#define HV_N  256
#define F_N   128

#define GRID      8192
#define WPB       4                             // waves per block
#define NSTREAM   (GRID * WPB)                  // 32768 waves in flight
#define NTASK     ((HV_N * (HV_N / 4)) * B_N)   // 262144 wave-tasks

typedef float v2f __attribute__((ext_vector_type(2)));

__global__ __launch_bounds__(256, 6) void spiking_conv2d_kernel(
    const float* __restrict__ tj, const float* __restrict__ kern,
    const float* __restrict__ Di, float* __restrict__ out) {
  const int lane = threadIdx.x & 63;
  const int wid  = __builtin_amdgcn_readfirstlane(threadIdx.x >> 6);

  // W[t][f], f = 2*lane, 2*lane+1. Registers, loaded once (per-lane vector ld).
  float2 w[9];
#pragma unroll
  for (int t = 0; t < 9; ++t)
    w[t] = reinterpret_cast<const float2*>(kern)[t * (F_N / 2) + lane];
  const float2 d = reinterpret_cast<const float2*>(Di)[lane];
  const float thx = 1.0f - d.x, thy = 1.0f - d.y;

  // task t: b = t&15, pblk = t>>4, j0 = (pblk&63)*4, i = pblk>>6
  auto load_task = [&](int t, float (&x)[18]) {
    const int b    = t & (B_N - 1);
    const int pblk = t >> 4;
    const int j0   = (pblk & 63) << 2;
    const int i    = pblk >> 6;
    const float* s = tj + (b * S_N + i) * S_N + j0;  // wave-uniform address
#pragma unroll
    for (int r = 0; r < 3; ++r)
#pragma unroll
      for (int c = 0; c < 6; ++c)
        x[r * 6 + c] = s[r * S_N + c];
  };

  auto compute_store = [&](int t, const float (&x)[18]) {
    const int b    = t & (B_N - 1);
    const int pblk = t >> 4;
    const int j0   = (pblk & 63) << 2;
    const int i    = pblk >> 6;
    const int n0   = ((i * HV_N + j0) << 4) | b;  // row id, < 2^20
    v2f* o = reinterpret_cast<v2f*>(out) + (long)n0 * (F_N / 2) + lane;
#pragma unroll
    for (int p = 0; p < 4; ++p) {
      float ax = thx, ay = thy;
#pragma unroll
      for (int r = 0; r < 3; ++r)
#pragma unroll
        for (int c = 0; c < 3; ++c) {         // tap order == R2 kernel:
          const float xv = x[r * 6 + p + c];  // bitwise-identical results
          ax = fmaf(xv, w[r * 3 + c].x, ax);
          ay = fmaf(xv, w[r * 3 + c].y, ay);
        }
      v2f v = {fminf(ax, 1.0f), fminf(ay, 1.0f)};
      // pixel p -> row n0 + 16p -> +p*1024 float2; wave writes 512B contiguous.
      // Plain store (NOT nontemporal): let L2 aggregate full lines.
      o[p * (16 * (F_N / 2))] = v;
    }
  };

  float xa[18], xb[18];
  int t = blockIdx.x * WPB + wid;
  if (t >= NTASK) return;  // defensive; exact with GRID=8192
  load_task(t, xa);
#pragma unroll 1
  for (; t + NSTREAM < NTASK; ) {
    load_task(t + NSTREAM, xb);     // prefetch next while computing current
    compute_store(t, xa);
    t += NSTREAM;
    if (t + NSTREAM < NTASK) {
      load_task(t + NSTREAM, xa);   // prefetch next-next
      compute_store(t, xb);
      t += NSTREAM;
    } else {
      compute_store(t, xb);
      t += NSTREAM;  // terminates loop
    }
  }
  if (t < NTASK) compute_store(t, xa);  // tail (not hit with exact config)
}

extern "C" void kernel_launch(void* const* d_in, const int* in_sizes, int n_in,
                              void* d_out, int out_size, void* d_ws, size_t ws_size,
                              hipStream_t stream) {
  const float* tj   = (const float*)d_in[0];
  const float* kern = (const float*)d_in[1];
  const float* Di   = (const float*)d_in[2];
  float* out = (float*)d_out;
  spiking_conv2d_kernel<<<GRID, 256, 0, stream>>>(tj, kern, Di, out);
}